// Round 5
// baseline (200.994 us; speedup 1.0000x reference)
//
#include <hip/hip_runtime.h>
#include <hip/hip_bf16.h>
#include <stdint.h>

#define B_   4
#define N_   10000
#define K_   16
#define D_   256
#define OUT_ 256
#define M_   (B_ * N_)          // 40000

// y2c: bf16, 16 chunks of 16 cols; row = (n*4+b), 32 B/row, 1.28 MB/chunk
#define C16_ELEMS ((size_t)M_ * 16)     // 640,000 ushorts per chunk
// y1c: fp32,  32 chunks of  8 cols; row = (n*4+b), 32 B/row, 1.28 MB/chunk
#define C8_ELEMS  ((size_t)M_ * 8)      // 320,000 floats per chunk

typedef __attribute__((ext_vector_type(8))) short          short8;    // MFMA frag
typedef __attribute__((ext_vector_type(8))) unsigned short ushort8;
typedef __attribute__((ext_vector_type(4))) float          f32x4;
typedef __attribute__((ext_vector_type(4))) unsigned short ushort4_t;

__device__ inline unsigned short f2bf(float f) {
    __hip_bfloat16 h = __float2bfloat16(f);
    return *reinterpret_cast<unsigned short*>(&h);
}
__device__ inline float bf2f(unsigned short u) {
    unsigned int v = ((unsigned int)u) << 16;
    return __builtin_bit_cast(float, v);
}

// ---------------------------------------------------------------------------
// wprep: W (256 x 512 f32, row o = [W1_o | W2_o]) -> WbF bf16 in FRAG-MAJOR
// order: WbF[(((o16*8 + kf)*64 + lane)*8 + e] = W'[o16*16 + (lane&15)]
//                                                  [kf*32 + (lane>>4)*8 + e]
// i.e. each (o16,kf) fragment is one coalesced 16-B load per lane, directly
// in mfma_16x16x32 A-operand layout (row = lane&15, k = (lane>>4)*8+e).
// W'[o'] = o'<256 ? W[o'][0:256] : W[o'-256][256:512].  Total 256 KB.
// ---------------------------------------------------------------------------
__global__ __launch_bounds__(256) void wprep(const float* __restrict__ W,
                                             unsigned short* __restrict__ WbF) {
    const int u  = blockIdx.x * 256 + threadIdx.x;   // 0..32767, 4 elems each
    const int e0 = (u & 1) * 4;
    const int l  = (u >> 1) & 63;
    const int v  = u >> 7;
    const int kf = v & 7;
    const int o16 = v >> 3;                          // 0..31
    const int op  = o16 * 16 + (l & 15);             // 0..511
    const int k   = kf * 32 + (l >> 4) * 8 + e0;     // 0..255
    const int row = (op < OUT_) ? op : op - OUT_;
    const int col = (op < OUT_) ? k : 256 + k;
    const float4 w4 = *(const float4*)(W + (size_t)row * 512 + col);
    ushort4_t s;
    s.x = f2bf(w4.x); s.y = f2bf(w4.y); s.z = f2bf(w4.z); s.w = f2bf(w4.w);
    *(ushort4_t*)(WbF + (size_t)u * 4) = s;
}

// ---------------------------------------------------------------------------
// gemm_regB: y[m, o'] = x[m, :] . W'[o', :]   (M=40000, K=256, N'=512)
// NO LDS, NO barriers. Each wave holds its 64 o-cols x 256 k of W' in 128
// VGPRs of B-fragments (loaded once from frag-major WbF, L2/L3-hot), then
// loops over 16-row m-groups: 16 independent dwordx4 x-loads -> cvt bf16 ->
// 32 MFMA (swapped operands: D[row=o, col=m]) -> packed chunked stores.
// Latency hidden by 16-deep load ILP + 2 blocks/CU TLP, not barriers.
// Grid 512 = 8 xcd x 2 half x 32 slot; both halves of an m-group share an
// XCD (x fetched from HBM once, sibling reads hit that XCD's L2).
//   half 0 -> y1c fp32 CW8 chunks; half 1 -> y2c bf16 CW16 chunks.
// ---------------------------------------------------------------------------
__global__ __launch_bounds__(256) void gemm_regB(const float* __restrict__ x,
                                                 const unsigned short* __restrict__ WbF,
                                                 float* __restrict__ y1c,
                                                 unsigned short* __restrict__ y2c) {
    const int tid  = threadIdx.x;
    const int wid  = tid >> 6;
    const int lane = tid & 63;
    const int q    = lane >> 4;
    const int r16  = lane & 15;

    const int bi   = blockIdx.x;
    const int xcd  = bi & 7;
    const int half = (bi >> 3) & 1;
    const int slot = bi >> 4;              // 0..31

    // ---- B fragments, once per block (32 coalesced 16-B loads/lane) ----
    short8 Bfr[4][8];
    const int o16b = half * 16 + wid * 4;
#pragma unroll
    for (int j = 0; j < 4; ++j)
#pragma unroll
        for (int kf = 0; kf < 8; ++kf)
            Bfr[j][kf] = *(const short8*)(
                WbF + (((size_t)(o16b + j) * 8 + kf) * 64 + lane) * 8);

    for (int g = xcd + 8 * slot; g < 2500; g += 256) {
        const int m0 = g * 16;
        const float* xr = x + (size_t)(m0 + r16) * D_ + q * 8;

        // 16 independent x loads (issued together; compiler waits finely)
        float4 xb[16];
#pragma unroll
        for (int kf = 0; kf < 8; ++kf) {
            xb[2 * kf]     = *(const float4*)(xr + kf * 32);
            xb[2 * kf + 1] = *(const float4*)(xr + kf * 32 + 4);
        }

        f32x4 acc[4] = {};
#pragma unroll
        for (int kf = 0; kf < 8; ++kf) {
            short8 a;
            a[0] = (short)f2bf(xb[2 * kf].x);     a[1] = (short)f2bf(xb[2 * kf].y);
            a[2] = (short)f2bf(xb[2 * kf].z);     a[3] = (short)f2bf(xb[2 * kf].w);
            a[4] = (short)f2bf(xb[2 * kf + 1].x); a[5] = (short)f2bf(xb[2 * kf + 1].y);
            a[6] = (short)f2bf(xb[2 * kf + 1].z); a[7] = (short)f2bf(xb[2 * kf + 1].w);
#pragma unroll
            for (int j = 0; j < 4; ++j)
                acc[j] = __builtin_amdgcn_mfma_f32_16x16x32_bf16(Bfr[j][kf], a, acc[j], 0, 0, 0);
        }

        // ---- chunked stores (lane holds 4 consecutive o-cols for m=r16) ----
        const int m  = m0 + r16;
        const int bb = (m >= N_) + (m >= 2 * N_) + (m >= 3 * N_);
        const int n  = m - bb * N_;
        const size_t row = (size_t)(n * B_ + bb);
        if (half == 0) {
#pragma unroll
            for (int j = 0; j < 4; ++j) {
                const int o2 = wid * 64 + j * 16 + q * 4;
                f32x4 p;
                p[0] = acc[j][0]; p[1] = acc[j][1];
                p[2] = acc[j][2]; p[3] = acc[j][3];
                *(f32x4*)(y1c + (size_t)(o2 >> 3) * C8_ELEMS + row * 8 + (o2 & 7)) = p;
            }
        } else {
#pragma unroll
            for (int j = 0; j < 4; ++j) {
                const int o2 = wid * 64 + j * 16 + q * 4;
                ushort4_t p;
                p.x = f2bf(acc[j][0]); p.y = f2bf(acc[j][1]);
                p.z = f2bf(acc[j][2]); p.w = f2bf(acc[j][3]);
                *(ushort4_t*)(y2c + (size_t)(o2 >> 4) * C16_ELEMS + row * 16 + (o2 & 15)) = p;
            }
        }
    }
}

// ---------------------------------------------------------------------------
// gather_out: out[b,n,o] = relu( y1[b,n,o] + (1/cnt) sum_k y2[b,neigh[n,k],o]
//                                + bias[o] )   — unchanged from round 4.
// Chunk c (16 cols) -> XCD c&7; per-XCD working set = y2 chunk (1.28 MB) +
// y1 chunks 2c,2c+1 (2.56 MB) = 3.84 MB < 4 MB L2.
// ---------------------------------------------------------------------------
__global__ __launch_bounds__(128) void gather_out(const unsigned short* __restrict__ y2c,
                                                  const float* __restrict__ y1c,
                                                  const int*   __restrict__ neigh,
                                                  const float* __restrict__ bias,
                                                  float* __restrict__ out) {
    const int bi  = blockIdx.x;
    const int lo  = bi < 5000;
    const int c   = (bi & 7) + (lo ? 0 : 8);          // chunk 0..15, XCD = c&7
    const int g   = (lo ? bi : bi - 5000) >> 3;       // 0..624
    const int n0  = g * 16;
    const int tid = threadIdx.x;

    __shared__ int   idx_s[16 * K_];   // 256 ints
    __shared__ float inv_s[16];

    idx_s[tid]       = neigh[n0 * K_ + tid];
    idx_s[tid + 128] = neigh[n0 * K_ + tid + 128];
    __syncthreads();
    if (tid < 16) {
        int cnt = 0;
#pragma unroll
        for (int k = 0; k < K_; ++k) cnt += idx_s[tid * K_ + k] >= 0 ? 1 : 0;
        inv_s[tid] = 1.0f / (float)(cnt > 1 ? cnt : 1);
    }
    __syncthreads();

    const int h  = tid & 1;          // col half (8 cols)
    const int tl = tid >> 1;         // task 0..63
    const int ns = tl >> 2;          // node_sub 0..15
    const int b  = tl & 3;           // batch

    const unsigned short* ycc = y2c + (size_t)c * C16_ELEMS;

    int jj[K_];
#pragma unroll
    for (int k = 0; k < K_; ++k) jj[k] = idx_s[ns * K_ + k];

    // 16 independent 16-B gather loads from the L2-resident chunk
    ushort8 vv[K_];
#pragma unroll
    for (int k = 0; k < K_; ++k) {
        const int jc = jj[k] >= 0 ? jj[k] : 0;
        vv[k] = *(const ushort8*)(ycc + ((size_t)jc * B_ + b) * 16 + h * 8);
    }

    // self term from the L2-resident y1 chunk (2c + h) + bias
    const size_t row = (size_t)((n0 + ns) * B_ + b);
    const float* yrow = y1c + (size_t)(2 * c + h) * C8_ELEMS + row * 8;
    const f32x4 s0 = *(const f32x4*)(yrow);
    const f32x4 s1 = *(const f32x4*)(yrow + 4);
    const f32x4 b0 = *(const f32x4*)(bias + c * 16 + h * 8);
    const f32x4 b1 = *(const f32x4*)(bias + c * 16 + h * 8 + 4);

    float acc[8] = {0.f, 0.f, 0.f, 0.f, 0.f, 0.f, 0.f, 0.f};
#pragma unroll
    for (int k = 0; k < K_; ++k) {
        const float m = jj[k] >= 0 ? 1.f : 0.f;
#pragma unroll
        for (int e = 0; e < 8; ++e) acc[e] += bf2f(vv[k][e]) * m;
    }
    const float inv = inv_s[ns];

    f32x4 o0, o1;
#pragma unroll
    for (int e = 0; e < 4; ++e) {
        float v0 = acc[e] * inv + s0[e] + b0[e];
        float v1 = acc[e + 4] * inv + s1[e] + b1[e];
        o0[e] = v0 > 0.f ? v0 : 0.f;
        o1[e] = v1 > 0.f ? v1 : 0.f;
    }
    // out: (b, n0+ns) row, cols c*16 + h*8 .. +8  (never re-read -> nt)
    float* op = out + ((size_t)b * N_ + n0 + ns) * OUT_ + c * 16 + h * 8;
    __builtin_nontemporal_store(o0, (f32x4*)op);
    __builtin_nontemporal_store(o1, (f32x4*)(op + 4));
}

// ---------------------------------------------------------------------------
extern "C" void kernel_launch(void* const* d_in, const int* in_sizes, int n_in,
                              void* d_out, int out_size, void* d_ws, size_t ws_size,
                              hipStream_t stream) {
    const float* x     = (const float*)d_in[0];   // (4, 10000, 256) fp32
    const int*   neigh = (const int*)d_in[1];     // (10000, 16) int32
    const float* W     = (const float*)d_in[2];   // (256, 512) fp32
    const float* bias  = (const float*)d_in[3];   // (256,) fp32
    float*       out   = (float*)d_out;           // (4, 10000, 256) fp32

    unsigned short* WbF = (unsigned short*)d_ws;              // 256 KB frag-major
    float*          y1c = (float*)(WbF + 131072);             // 32 x 1.28 MB = 41 MB
    unsigned short* y2c = (unsigned short*)(y1c + 32 * C8_ELEMS); // 16 x 1.28 MB

    wprep<<<128, 256, 0, stream>>>(W, WbF);
    gemm_regB<<<512, 256, 0, stream>>>(x, WbF, y1c, y2c);
    gather_out<<<10000, 128, 0, stream>>>(y2c, y1c, neigh, bias, out);
}

// Round 6
// 142.952 us; speedup vs baseline: 1.4060x; 1.4060x over previous
//
#include <hip/hip_runtime.h>
#include <hip/hip_bf16.h>
#include <stdint.h>

#define B_   4
#define N_   10000
#define K_   16
#define D_   256
#define OUT_ 256
#define KDIM 512                // 2*D
#define M_   (B_ * N_)          // 40000
#define CW   32                 // bf16 cols per y2 chunk (64-B rows)
#define NCH  8                  // chunks (one per XCD)
#define CHUNK_ELEMS ((size_t)M_ * CW)   // 1,280,000 ushorts = 2.56 MB
#define T32_ 1250               // M / 32 m-tiles, exact

typedef __attribute__((ext_vector_type(8))) short          short8;    // MFMA frag
typedef __attribute__((ext_vector_type(8))) unsigned short ushort8;
typedef __attribute__((ext_vector_type(4))) float          f32x4;
typedef __attribute__((ext_vector_type(4))) unsigned short ushort4_t;

__device__ inline unsigned short f2bf(float f) {
    __hip_bfloat16 h = __float2bfloat16(f);
    return *reinterpret_cast<unsigned short*>(&h);
}
__device__ inline float bf2f(unsigned short u) {
    unsigned int v = ((unsigned int)u) << 16;
    return __builtin_bit_cast(float, v);
}

// ---------------------------------------------------------------------------
// wprep (R1 version, proven): W (256 x 512 f32, row o = [W1_o | W2_o]) ->
// Wb (512 x 256 bf16):  Wb[o][k] = W[o][k],  Wb[256+o][k] = W[o][256+k].
// ---------------------------------------------------------------------------
__global__ __launch_bounds__(256) void wprep(const float* __restrict__ W,
                                             unsigned short* __restrict__ Wb) {
    const int g  = blockIdx.x * 256 + threadIdx.x;   // 0..32767
    const int op = g >> 6;                           // 0..511
    const int k0 = (g & 63) * 4;
    const float* src = (op < OUT_) ? (W + (size_t)op * 512 + k0)
                                   : (W + (size_t)(op - OUT_) * 512 + 256 + k0);
    const float4 v = *(const float4*)src;
    ushort4_t s;
    s.x = f2bf(v.x); s.y = f2bf(v.y); s.z = f2bf(v.z); s.w = f2bf(v.w);
    *(ushort4_t*)(Wb + (size_t)op * 256 + k0) = s;
}

// ---------------------------------------------------------------------------
// gemm32: y[m, o'] = x[m, :] . Wb[o', :]   (M=40000, K=256, N'=512)
// R1 gemm_fused structure with the tile halved to 32m x 256n -> 2500 blocks.
// Rationale: every 64-row variant sat at 19-33% occupancy (4.9 blocks/CU of
// supply); same 18-KB-LDS 2-barrier chain at 2x the block count doubles the
// independent chains per CU so the barrier drains finally overlap.
// 256 thr / 4 waves; wave w = 64-col strip. BK=32, 8 k-steps.
//   half 0 -> y1 fp32 m-row-major (normal mfma(a,b))          [R1 epilogue]
//   half 1 -> y2 bf16 CW32 chunk-major via swapped mfma(b,a),
//             packed 8-B ushort4 stores                        [R3 epilogue]
// Halves of an m-tile share an XCD (x fetched from HBM once).
// ---------------------------------------------------------------------------
__global__ __launch_bounds__(256) void gemm32(const float* __restrict__ x,
                                              const unsigned short* __restrict__ Wb,
                                              float* __restrict__ y1,
                                              unsigned short* __restrict__ y2c) {
    __shared__ unsigned short As[32 * 32];    //  2 KB
    __shared__ unsigned short Bs[256 * 32];   // 16 KB

    const int tid  = threadIdx.x;
    const int w    = tid >> 6;
    const int lane = tid & 63;
    const int q    = lane >> 4;
    const int r16  = lane & 15;

    // block -> (m-tile g, half); halves of g share an XCD
    const int bi   = blockIdx.x;
    const int xcd  = bi & 7;
    const int u    = bi >> 3;
    const int g    = (u >> 1) * 8 + xcd;
    const int half = u & 1;
    if (g >= T32_) return;
    const int tile_m = g * 32;

    // ---- A staging coords: 32 rows x 32 k fp32 = 1024 f32 / 256 thr ----
    const int arow  = tid >> 3;        // 0..31
    const int acol4 = (tid & 7) * 4;   // 0,4,...,28
    const float* xrow = x + (size_t)(tile_m + arow) * D_ + acol4;

    // ---- B staging: 16 chunks of 16 rows; wave w stages chunks w*4..w*4+3
    const int crow = lane >> 2;        // 0..15: row within a 16-row chunk
    const int kofs = (lane & 3) * 8;   // ushort offset within BK=32
    const unsigned short* bsrc =
        Wb + ((size_t)(half * OUT_) + crow) * D_ + kofs;

    f32x4 acc[2][4] = {};

    // prefetch first A sub-tile into regs
    float4 va = *(const float4*)(xrow);

    for (int kk = 0; kk < D_; kk += 32) {
        // issue B global->LDS (4 chunks per wave, stay in flight to barrier)
#pragma unroll
        for (int t = 0; t < 4; ++t) {
            const int c = w * 4 + t;
            __builtin_amdgcn_global_load_lds(
                (const __attribute__((address_space(1))) void*)(bsrc + (size_t)c * 16 * D_ + kk),
                (__attribute__((address_space(3))) void*)(Bs + c * 512),
                16, 0, 0);
        }
        // convert current A regs -> LDS (8 B per thread, linear)
        ushort4_t s;
        s.x = f2bf(va.x); s.y = f2bf(va.y); s.z = f2bf(va.z); s.w = f2bf(va.w);
        *(ushort4_t*)(As + arow * 32 + acol4) = s;
        // prefetch next A sub-tile (overlaps barrier drain + MFMA)
        if (kk + 32 < D_) va = *(const float4*)(xrow + kk + 32);
        __syncthreads();

        short8 a[2], bf[4];
#pragma unroll
        for (int i = 0; i < 2; ++i)
            a[i] = *(const short8*)(As + (i * 16 + r16) * 32 + q * 8);
#pragma unroll
        for (int j = 0; j < 4; ++j)
            bf[j] = *(const short8*)(Bs + (w * 64 + j * 16 + r16) * 32 + q * 8);

        if (half == 0) {
#pragma unroll
            for (int i = 0; i < 2; ++i)
#pragma unroll
                for (int j = 0; j < 4; ++j)
                    acc[i][j] = __builtin_amdgcn_mfma_f32_16x16x32_bf16(a[i], bf[j], acc[i][j], 0, 0, 0);
        } else {
#pragma unroll
            for (int i = 0; i < 2; ++i)
#pragma unroll
                for (int j = 0; j < 4; ++j)
                    acc[i][j] = __builtin_amdgcn_mfma_f32_16x16x32_bf16(bf[j], a[i], acc[i][j], 0, 0, 0);
        }

        __syncthreads();
    }

    // ---- epilogue ----
    if (half == 0) {
        // D[row = q*4+reg (m), col = r16 (o)] : y1 fp32 m-row-major
#pragma unroll
        for (int i = 0; i < 2; ++i) {
#pragma unroll
            for (int reg = 0; reg < 4; ++reg) {
                const int m = tile_m + i * 16 + q * 4 + reg;
                float* row = y1 + (size_t)m * OUT_ + w * 64;
#pragma unroll
                for (int j = 0; j < 4; ++j)
                    row[j * 16 + r16] = acc[i][j][reg];
            }
        }
    } else {
        // swapped: D[row = q*4+reg (o), col = r16 (m)] -> packed ushort4
#pragma unroll
        for (int i = 0; i < 2; ++i) {
            const int m  = tile_m + i * 16 + r16;
            const int bb = (m >= N_) + (m >= 2 * N_) + (m >= 3 * N_);
            const int n  = m - bb * N_;
            unsigned short* rb = y2c + (size_t)(n * B_ + bb) * CW;
#pragma unroll
            for (int j = 0; j < 4; ++j) {
                const int o2  = w * 64 + j * 16 + q * 4;   // 4 consecutive cols
                const int cch = o2 >> 5;
                const int col = o2 & 31;
                ushort4_t p;
                p.x = f2bf(acc[i][j][0]); p.y = f2bf(acc[i][j][1]);
                p.z = f2bf(acc[i][j][2]); p.w = f2bf(acc[i][j][3]);
                *(ushort4_t*)(rb + (size_t)cch * CHUNK_ELEMS + col) = p;
            }
        }
    }
}

// ---------------------------------------------------------------------------
// gather_out (R1 structure + NT y1 loads): out[b,n,o] =
//   relu( y1[b,n,o] + (1/cnt) sum_k y2[b,neigh[n,k],o] + bias[o] )
// Chunk c = blockIdx&7 -> XCD; 2.56-MB y2 chunk L2-resident. y1 is read
// exactly once -> NONTEMPORAL loads so the 41-MB stream doesn't evict the
// gather chunk from L2 (the diagnosed cause of gather's ~50 us).
// ---------------------------------------------------------------------------
__global__ __launch_bounds__(256) void gather_out(const unsigned short* __restrict__ y2c,
                                                  const float* __restrict__ y1,
                                                  const int*   __restrict__ neigh,
                                                  const float* __restrict__ bias,
                                                  float* __restrict__ out) {
    const int c   = blockIdx.x & 7;
    const int g   = blockIdx.x >> 3;
    const int n0  = g * 16;
    const int tid = threadIdx.x;

    __shared__ int   idx_s[16 * K_];   // 256 ints
    __shared__ float inv_s[16];

    idx_s[tid] = neigh[n0 * K_ + tid];
    __syncthreads();
    if (tid < 16) {
        int cnt = 0;
#pragma unroll
        for (int k = 0; k < K_; ++k) cnt += idx_s[tid * K_ + k] >= 0 ? 1 : 0;
        inv_s[tid] = 1.0f / (float)(cnt > 1 ? cnt : 1);
    }
    __syncthreads();

    const int q  = tid & 3;          // 8-col group within the 32-col chunk
    const int tl = tid >> 2;         // task 0..63
    const int ns = tl >> 2;          // node_sub 0..15
    const int b  = tl & 3;           // batch

    const unsigned short* ycc = y2c + (size_t)c * CHUNK_ELEMS;

    int jj[K_];
#pragma unroll
    for (int k = 0; k < K_; ++k) jj[k] = idx_s[ns * K_ + k];

    // 16 independent 16-B gather loads from the L2-resident chunk
    ushort8 vv[K_];
#pragma unroll
    for (int k = 0; k < K_; ++k) {
        const int jc = jj[k] >= 0 ? jj[k] : 0;
        vv[k] = *(const ushort8*)(ycc + ((size_t)jc * B_ + b) * CW + q * 8);
    }

    // streaming self term (NT: read-once, keep L2 for the chunk) + bias
    const size_t mo = (size_t)(b * N_ + n0 + ns) * OUT_ + c * CW + q * 8;
    const f32x4 s0 = __builtin_nontemporal_load((const f32x4*)(y1 + mo));
    const f32x4 s1 = __builtin_nontemporal_load((const f32x4*)(y1 + mo + 4));
    const f32x4 b0 = *(const f32x4*)(bias + c * CW + q * 8);
    const f32x4 b1 = *(const f32x4*)(bias + c * CW + q * 8 + 4);

    float acc[8] = {0.f, 0.f, 0.f, 0.f, 0.f, 0.f, 0.f, 0.f};
#pragma unroll
    for (int k = 0; k < K_; ++k) {
        const float m = jj[k] >= 0 ? 1.f : 0.f;
#pragma unroll
        for (int e = 0; e < 8; ++e) acc[e] += bf2f(vv[k][e]) * m;
    }
    const float inv = inv_s[ns];

    f32x4 o0, o1;
#pragma unroll
    for (int e = 0; e < 4; ++e) {
        float v0 = acc[e] * inv + s0[e] + b0[e];
        float v1 = acc[e + 4] * inv + s1[e] + b1[e];
        o0[e] = v0 > 0.f ? v0 : 0.f;
        o1[e] = v1 > 0.f ? v1 : 0.f;
    }
    // out is never re-read: nontemporal stores
    __builtin_nontemporal_store(o0, (f32x4*)(out + mo));
    __builtin_nontemporal_store(o1, (f32x4*)(out + mo + 4));
}

// ---------------------------------------------------------------------------
extern "C" void kernel_launch(void* const* d_in, const int* in_sizes, int n_in,
                              void* d_out, int out_size, void* d_ws, size_t ws_size,
                              hipStream_t stream) {
    const float* x     = (const float*)d_in[0];   // (4, 10000, 256) fp32
    const int*   neigh = (const int*)d_in[1];     // (10000, 16) int32
    const float* W     = (const float*)d_in[2];   // (256, 512) fp32
    const float* bias  = (const float*)d_in[3];   // (256,) fp32
    float*       out   = (float*)d_out;           // (4, 10000, 256) fp32

    unsigned short* Wb  = (unsigned short*)d_ws;          // 512*256 bf16 = 0.26 MB
    float*          y1  = (float*)(Wb + 512 * D_);        // 40000*256 f32 = 40.96 MB
    unsigned short* y2c = (unsigned short*)(y1 + (size_t)M_ * OUT_);  // 8 x 2.56 MB

    wprep<<<128, 256, 0, stream>>>(W, Wb);
    // 1250 m-tiles x 2 halves, padded to pair-multiple of 8 XCDs: 157*8*2
    gemm32<<<157 * 8 * 2, 256, 0, stream>>>(x, Wb, y1, y2c);
    gather_out<<<(N_ / 16) * NCH, 256, 0, stream>>>(y2c, y1, neigh, bias, out);
}